// Round 3
// baseline (1540.472 us; speedup 1.0000x reference)
//
#include <hip/hip_runtime.h>

// HGCNConv: out = LeakyReLU_0.5( A @ (A^T @ embs) ), A sparse COO.
// N=100000, H=50000, D=128, NNZ=3200000.
//
// Single fused counting-sort (both groupings in one pass over edges), then
// one wave per output row doing a pure gather-reduce with scalar-pipe edge
// metadata loads (readfirstlane-forced uniform loop -> s_load) and one
// coalesced 512B vector row load per edge. No fp atomics anywhere.

#define HGCN_D   128
#define HGCN_H   50000
#define SCAN_TPB 256
#define SCAN_PER 2048   // 8 elements per thread

// ---- fused histogram: cnt[col] and cnt[H+row] ----------------------------
__global__ void hgcn_hist2(const int* __restrict__ rows, const int* __restrict__ cols,
                           int* __restrict__ cnt, int nnz) {
    int i = blockIdx.x * blockDim.x + threadIdx.x;
    if (i < nnz) {
        atomicAdd(&cnt[cols[i]], 1);
        atomicAdd(&cnt[HGCN_H + rows[i]], 1);
    }
}

// ---- hierarchical exclusive scan over cnt[0..n) (in-place) ---------------
__global__ void hgcn_scan_reduce(const int* __restrict__ cnt, int* __restrict__ partial, int n) {
    __shared__ int red[SCAN_TPB];
    int base = blockIdx.x * SCAN_PER;
    int sum = 0;
    for (int k = threadIdx.x; k < SCAN_PER; k += SCAN_TPB) {
        int i = base + k;
        if (i < n) sum += cnt[i];
    }
    red[threadIdx.x] = sum; __syncthreads();
    for (int o = SCAN_TPB / 2; o > 0; o >>= 1) {
        if (threadIdx.x < o) red[threadIdx.x] += red[threadIdx.x + o];
        __syncthreads();
    }
    if (threadIdx.x == 0) partial[blockIdx.x] = red[0];
}

__global__ void hgcn_scan_partials(int* __restrict__ partial, int nb) {
    __shared__ int buf[SCAN_TPB];
    int tid = threadIdx.x;
    int x = (tid < nb) ? partial[tid] : 0;
    buf[tid] = x; __syncthreads();
    for (int o = 1; o < SCAN_TPB; o <<= 1) {
        int y = (tid >= o) ? buf[tid - o] : 0;
        __syncthreads();
        buf[tid] += y;
        __syncthreads();
    }
    if (tid < nb) partial[tid] = buf[tid] - x;   // exclusive
}

__global__ void hgcn_scan_apply(int* __restrict__ cnt, const int* __restrict__ partial, int n) {
    __shared__ int buf[SCAN_TPB];
    int base = blockIdx.x * SCAN_PER + threadIdx.x * 8;
    int v[8]; int s = 0;
    #pragma unroll
    for (int k = 0; k < 8; ++k) {
        int i = base + k;
        v[k] = (i < n) ? cnt[i] : 0;
        s += v[k];
    }
    buf[threadIdx.x] = s; __syncthreads();
    int x = s;
    for (int o = 1; o < SCAN_TPB; o <<= 1) {
        int y = (threadIdx.x >= o) ? buf[threadIdx.x - o] : 0;
        __syncthreads();
        buf[threadIdx.x] += y;
        __syncthreads();
    }
    int excl = buf[threadIdx.x] - x + partial[blockIdx.x];
    #pragma unroll
    for (int k = 0; k < 8; ++k) {
        int i = base + k;
        if (i < n) { cnt[i] = excl; excl += v[k]; }
    }
}

// ---- fused ticketed scatter: perm[pos] = edge id, both orderings ---------
// after this kernel, cnt[k] == END offset of bucket k.
__global__ void hgcn_scat2(const int* __restrict__ rows, const int* __restrict__ cols,
                           int* __restrict__ cur, int* __restrict__ perm, int nnz) {
    int i = blockIdx.x * blockDim.x + threadIdx.x;
    if (i < nnz) {
        int c = cols[i], r = rows[i];
        int pA = atomicAdd(&cur[c], 1);
        perm[pA] = i;
        int pB = atomicAdd(&cur[HGCN_H + r], 1);
        perm[pB] = i;
    }
}

// ---- gather-reduce: one 64-lane wave per output row ----------------------
// wid forced uniform -> loop bounds, perm[j], vals[e], other[e] are scalar
// (SMEM pipe). Vector pipe: one coalesced 512B row load + 2 FMAs per edge.
template <int RELU>
__global__ void hgcn_gather(const int* __restrict__ perm, const int* __restrict__ cnt,
                            const float* __restrict__ vals, const int* __restrict__ other,
                            const float* __restrict__ src, float* __restrict__ dst,
                            int n_dst, int bucket0) {
    int wpb = blockDim.x >> 6;
    int wid = __builtin_amdgcn_readfirstlane((int)(blockIdx.x * wpb + (threadIdx.x >> 6)));
    if (wid >= n_dst) return;
    int lane = threadIdx.x & 63;
    int bk = bucket0 + wid;
    int s_ = (bk == 0) ? 0 : cnt[bk - 1];
    int e_ = cnt[bk];

    const float2* srcv = (const float2*)src;
    float2 a0 = make_float2(0.f, 0.f), a1 = make_float2(0.f, 0.f);
    int j = s_;
    for (; j + 1 < e_; j += 2) {
        int e0 = perm[j], e1 = perm[j + 1];
        float v0 = vals[e0], v1 = vals[e1];
        int i0 = other[e0], i1 = other[e1];
        float2 x0 = srcv[i0 * 64 + lane];
        float2 x1 = srcv[i1 * 64 + lane];
        a0.x += v0 * x0.x; a0.y += v0 * x0.y;
        a1.x += v1 * x1.x; a1.y += v1 * x1.y;
    }
    if (j < e_) {
        int e0 = perm[j];
        float v0 = vals[e0];
        int i0 = other[e0];
        float2 x0 = srcv[i0 * 64 + lane];
        a0.x += v0 * x0.x; a0.y += v0 * x0.y;
    }
    float2 r = make_float2(a0.x + a1.x, a0.y + a1.y);
    if (RELU) {
        r.x = r.x >= 0.f ? r.x : 0.5f * r.x;
        r.y = r.y >= 0.f ? r.y : 0.5f * r.y;
    }
    ((float2*)dst)[wid * 64 + lane] = r;
}

extern "C" void kernel_launch(void* const* d_in, const int* in_sizes, int n_in,
                              void* d_out, int out_size, void* d_ws, size_t ws_size,
                              hipStream_t stream) {
    const float* vals = (const float*)d_in[0];
    const float* embs = (const float*)d_in[1];
    const int*   rows = (const int*)d_in[2];
    const int*   cols = (const int*)d_in[3];

    const int nnz     = in_sizes[0];
    const int n_nodes = in_sizes[1] / HGCN_D;   // 100000
    const int n_all   = HGCN_H + n_nodes;       // 150000 buckets total

    float* out = (float*)d_out;

    // workspace: hyper [H*D] | perm [2*nnz] | cnt [n_all] | partial
    char* ws = (char*)d_ws;
    float* hyper = (float*)ws;
    size_t off = (size_t)HGCN_H * HGCN_D * sizeof(float);
    int* perm = (int*)(ws + off);
    off += (size_t)2 * nnz * sizeof(int);
    off = (off + 255) & ~(size_t)255;
    int* cnt = (int*)(ws + off);
    off += (size_t)n_all * sizeof(int);
    off = (off + 255) & ~(size_t)255;
    int* partial = (int*)(ws + off);

    const int B = 256;
    int eg = (nnz + B - 1) / B;
    int nb = (n_all + SCAN_PER - 1) / SCAN_PER;   // 74 <= 256

    hipMemsetAsync(cnt, 0, (size_t)n_all * sizeof(int), stream);
    hgcn_hist2<<<eg, B, 0, stream>>>(rows, cols, cnt, nnz);
    hgcn_scan_reduce<<<nb, SCAN_TPB, 0, stream>>>(cnt, partial, n_all);
    hgcn_scan_partials<<<1, SCAN_TPB, 0, stream>>>(partial, nb);
    hgcn_scan_apply<<<nb, SCAN_TPB, 0, stream>>>(cnt, partial, n_all);
    hgcn_scat2<<<eg, B, 0, stream>>>(rows, cols, cnt, perm, nnz);

    // phase 1: hyper[c] = sum val*embs[r]   (buckets [0, H))
    hgcn_gather<0><<<(HGCN_H + 3) / 4, 256, 0, stream>>>(perm, cnt, vals, rows,
                                                         embs, hyper, HGCN_H, 0);
    // phase 2: out[r] = LeakyReLU(sum val*hyper[c])   (buckets [H, H+N))
    hgcn_gather<1><<<(n_nodes + 3) / 4, 256, 0, stream>>>(perm, cnt, vals, cols,
                                                          hyper, out, n_nodes, HGCN_H);
}

// Round 4
// 1444.474 us; speedup vs baseline: 1.0665x; 1.0665x over previous
//
#include <hip/hip_runtime.h>

// HGCNConv: out = LeakyReLU_0.5( A @ (A^T @ embs) ), A sparse COO.
// N=100000, H=50000, D=128, NNZ=3200000.
//
// Counting-sort into per-bucket edge lists (no fp atomics), then one wave per
// output row does a gather-reduce (scalar-pipe metadata, one coalesced 512B
// row load per edge). Round-4 changes: separate scatter streams (round-3
// fusion halved HBM write efficiency), scat_rows overlapped with gather1 via
// interleaved block roles, gather unrolled x4.

#define HGCN_D   128
#define HGCN_H   50000
#define SCAN_TPB 256
#define SCAN_PER 2048   // 8 elements per thread

// ---- fused histogram: cnt[col] and cnt[H+row] ----------------------------
__global__ void hgcn_hist2(const int* __restrict__ rows, const int* __restrict__ cols,
                           int* __restrict__ cnt, int nnz) {
    int i = blockIdx.x * blockDim.x + threadIdx.x;
    if (i < nnz) {
        atomicAdd(&cnt[cols[i]], 1);
        atomicAdd(&cnt[HGCN_H + rows[i]], 1);
    }
}

// ---- hierarchical exclusive scan over cnt[0..n) (in-place) ---------------
__global__ void hgcn_scan_reduce(const int* __restrict__ cnt, int* __restrict__ partial, int n) {
    __shared__ int red[SCAN_TPB];
    int base = blockIdx.x * SCAN_PER;
    int sum = 0;
    for (int k = threadIdx.x; k < SCAN_PER; k += SCAN_TPB) {
        int i = base + k;
        if (i < n) sum += cnt[i];
    }
    red[threadIdx.x] = sum; __syncthreads();
    for (int o = SCAN_TPB / 2; o > 0; o >>= 1) {
        if (threadIdx.x < o) red[threadIdx.x] += red[threadIdx.x + o];
        __syncthreads();
    }
    if (threadIdx.x == 0) partial[blockIdx.x] = red[0];
}

__global__ void hgcn_scan_partials(int* __restrict__ partial, int nb) {
    __shared__ int buf[SCAN_TPB];
    int tid = threadIdx.x;
    int x = (tid < nb) ? partial[tid] : 0;
    buf[tid] = x; __syncthreads();
    for (int o = 1; o < SCAN_TPB; o <<= 1) {
        int y = (tid >= o) ? buf[tid - o] : 0;
        __syncthreads();
        buf[tid] += y;
        __syncthreads();
    }
    if (tid < nb) partial[tid] = buf[tid] - x;   // exclusive
}

__global__ void hgcn_scan_apply(int* __restrict__ cnt, const int* __restrict__ partial, int n) {
    __shared__ int buf[SCAN_TPB];
    int base = blockIdx.x * SCAN_PER + threadIdx.x * 8;
    int v[8]; int s = 0;
    #pragma unroll
    for (int k = 0; k < 8; ++k) {
        int i = base + k;
        v[k] = (i < n) ? cnt[i] : 0;
        s += v[k];
    }
    buf[threadIdx.x] = s; __syncthreads();
    int x = s;
    for (int o = 1; o < SCAN_TPB; o <<= 1) {
        int y = (threadIdx.x >= o) ? buf[threadIdx.x - o] : 0;
        __syncthreads();
        buf[threadIdx.x] += y;
        __syncthreads();
    }
    int excl = buf[threadIdx.x] - x + partial[blockIdx.x];
    #pragma unroll
    for (int k = 0; k < 8; ++k) {
        int i = base + k;
        if (i < n) { cnt[i] = excl; excl += v[k]; }
    }
}

// ---- ticketed scatter, cols only (perm positions [0, nnz)) ---------------
__global__ void hgcn_scat_cols(const int* __restrict__ cols, int* __restrict__ cur,
                               int* __restrict__ perm, int nnz) {
    int i = blockIdx.x * blockDim.x + threadIdx.x;
    if (i < nnz) {
        int p = atomicAdd(&cur[cols[i]], 1);
        perm[p] = i;
    }
}

// ---- gather-reduce body: one 64-lane wave per output row -----------------
// wid uniform (readfirstlane) -> perm/vals/other loads hit the scalar pipe;
// vector pipe does one coalesced 512B row load + 2 FMAs per edge. Unroll x4.
template <int RELU>
__device__ __forceinline__ void hgcn_gather_row(
        const int* __restrict__ perm, const int* __restrict__ cnt,
        const float* __restrict__ vals, const int* __restrict__ other,
        const float* __restrict__ src, float* __restrict__ dst,
        int wid, int lane, int bucket0) {
    int bk = bucket0 + wid;
    int s_ = (bk == 0) ? 0 : cnt[bk - 1];
    int e_ = cnt[bk];

    const float2* srcv = (const float2*)src;
    float2 a0 = make_float2(0.f, 0.f), a1 = make_float2(0.f, 0.f);
    float2 a2 = make_float2(0.f, 0.f), a3 = make_float2(0.f, 0.f);
    int j = s_;
    for (; j + 3 < e_; j += 4) {
        int e0 = perm[j], e1 = perm[j + 1], e2 = perm[j + 2], e3 = perm[j + 3];
        float v0 = vals[e0], v1 = vals[e1], v2 = vals[e2], v3 = vals[e3];
        int i0 = other[e0], i1 = other[e1], i2 = other[e2], i3 = other[e3];
        float2 x0 = srcv[i0 * 64 + lane];
        float2 x1 = srcv[i1 * 64 + lane];
        float2 x2 = srcv[i2 * 64 + lane];
        float2 x3 = srcv[i3 * 64 + lane];
        a0.x += v0 * x0.x; a0.y += v0 * x0.y;
        a1.x += v1 * x1.x; a1.y += v1 * x1.y;
        a2.x += v2 * x2.x; a2.y += v2 * x2.y;
        a3.x += v3 * x3.x; a3.y += v3 * x3.y;
    }
    for (; j < e_; ++j) {
        int e0 = perm[j];
        float v0 = vals[e0];
        int i0 = other[e0];
        float2 x0 = srcv[i0 * 64 + lane];
        a0.x += v0 * x0.x; a0.y += v0 * x0.y;
    }
    float2 r = make_float2((a0.x + a1.x) + (a2.x + a3.x),
                           (a0.y + a1.y) + (a2.y + a3.y));
    if (RELU) {
        r.x = r.x >= 0.f ? r.x : 0.5f * r.x;
        r.y = r.y >= 0.f ? r.y : 0.5f * r.y;
    }
    ((float2*)dst)[wid * 64 + lane] = r;
}

// ---- fused: gather phase-1 (cols buckets -> hyper)  +  scat_rows ---------
// Independent work; interleaved block roles so the LLC-read-bound gather and
// the HBM-write-bound scatter overlap instead of serializing.
__global__ void hgcn_g1_scatrows(const int* __restrict__ perm, int* __restrict__ cnt,
                                 const float* __restrict__ vals,
                                 const int* __restrict__ rows,
                                 const float* __restrict__ embs,
                                 float* __restrict__ hyper,
                                 int nnz, int nb_g, int nb_s) {
    int b = blockIdx.x;
    int m2 = (nb_g < nb_s ? nb_g : nb_s) * 2;
    int role, idx;
    if (b < m2) { role = b & 1; idx = b >> 1; }
    else {
        int r = b - m2;
        if (nb_g > nb_s) { role = 0; idx = (m2 >> 1) + r; }
        else             { role = 1; idx = (m2 >> 1) + r; }
    }

    if (role == 0) {
        // gather phase 1: hyper[c] = sum val * embs[r], buckets [0, H)
        int wid = __builtin_amdgcn_readfirstlane(idx * 4 + (int)(threadIdx.x >> 6));
        if (wid >= HGCN_H) return;
        int lane = threadIdx.x & 63;
        hgcn_gather_row<0>(perm, cnt, vals, rows, embs, hyper, wid, lane, 0);
    } else {
        // scatter rows tickets into perm[nnz, 2*nnz)
        int i = idx * 256 + threadIdx.x;
        if (i < nnz) {
            int p = atomicAdd(&cnt[HGCN_H + rows[i]], 1);
            ((int*)perm)[p] = i;   // positions >= nnz by construction
        }
    }
}

// ---- gather phase-2: rows buckets -> out, with LeakyReLU -----------------
__global__ void hgcn_gather2(const int* __restrict__ perm, const int* __restrict__ cnt,
                             const float* __restrict__ vals, const int* __restrict__ cols,
                             const float* __restrict__ hyper, float* __restrict__ out,
                             int n_nodes) {
    int wid = __builtin_amdgcn_readfirstlane(
        (int)(blockIdx.x * 4 + (threadIdx.x >> 6)));
    if (wid >= n_nodes) return;
    int lane = threadIdx.x & 63;
    hgcn_gather_row<1>(perm, cnt, vals, cols, hyper, out, wid, lane, HGCN_H);
}

extern "C" void kernel_launch(void* const* d_in, const int* in_sizes, int n_in,
                              void* d_out, int out_size, void* d_ws, size_t ws_size,
                              hipStream_t stream) {
    const float* vals = (const float*)d_in[0];
    const float* embs = (const float*)d_in[1];
    const int*   rows = (const int*)d_in[2];
    const int*   cols = (const int*)d_in[3];

    const int nnz     = in_sizes[0];
    const int n_nodes = in_sizes[1] / HGCN_D;   // 100000
    const int n_all   = HGCN_H + n_nodes;       // 150000 buckets

    float* out = (float*)d_out;

    // workspace: hyper [H*D] | perm [2*nnz] | cnt [n_all] | partial  (~52 MB)
    char* ws = (char*)d_ws;
    float* hyper = (float*)ws;
    size_t off = (size_t)HGCN_H * HGCN_D * sizeof(float);
    int* perm = (int*)(ws + off);
    off += (size_t)2 * nnz * sizeof(int);
    off = (off + 255) & ~(size_t)255;
    int* cnt = (int*)(ws + off);
    off += (size_t)n_all * sizeof(int);
    off = (off + 255) & ~(size_t)255;
    int* partial = (int*)(ws + off);

    const int B = 256;
    int eg = (nnz + B - 1) / B;                    // 12500
    int nb = (n_all + SCAN_PER - 1) / SCAN_PER;    // 74

    hipMemsetAsync(cnt, 0, (size_t)n_all * sizeof(int), stream);
    hgcn_hist2<<<eg, B, 0, stream>>>(rows, cols, cnt, nnz);
    hgcn_scan_reduce<<<nb, SCAN_TPB, 0, stream>>>(cnt, partial, n_all);
    hgcn_scan_partials<<<1, SCAN_TPB, 0, stream>>>(partial, nb);
    hgcn_scan_apply<<<nb, SCAN_TPB, 0, stream>>>(cnt, partial, n_all);

    // cols tickets -> perm[0, nnz)
    hgcn_scat_cols<<<eg, B, 0, stream>>>(cols, cnt, perm, nnz);

    // gather1 (H buckets, 4 rows/block) overlapped with scat_rows
    int nb_g = (HGCN_H + 3) / 4;                   // 12500
    int nb_s = eg;                                 // 12500
    hgcn_g1_scatrows<<<nb_g + nb_s, B, 0, stream>>>(perm, cnt, vals, rows,
                                                    embs, hyper, nnz, nb_g, nb_s);

    // gather2 (N buckets) + LeakyReLU
    hgcn_gather2<<<(n_nodes + 3) / 4, B, 0, stream>>>(perm, cnt, vals, cols,
                                                      hyper, out, n_nodes);
}

// Round 5
// 1233.351 us; speedup vs baseline: 1.2490x; 1.1712x over previous
//
#include <hip/hip_runtime.h>

// HGCNConv: out = LeakyReLU_0.5( A @ (A^T @ embs) ), A sparse COO.
// N=100000, H=50000, D=128, NNZ=3200000.
//
// Counting-sort into per-bucket PACKED (val, other_idx) records, then one
// 64-lane wave per output row does a gather-reduce: contiguous scalar-pipe
// metadata loads (8B/edge, s_load_dwordx16 per 8 edges), one coalesced 512B
// vector row load + 2 FMAs per edge, unroll x8. No fp atomics anywhere.
// Round-5 change: perm stores (val,idx) pairs, not edge ids -> removes the
// random 4B vals[e]/other[e] metadata loads (scalar-cache thrash) that made
// the gathers latency-bound. Fallback to round-4 edge-id path if ws too small.

#define HGCN_D   128
#define HGCN_H   50000
#define SCAN_TPB 256
#define SCAN_PER 2048   // 8 elements per thread

// ---- fused histogram: cnt[col] and cnt[H+row] ----------------------------
__global__ void hgcn_hist2(const int* __restrict__ rows, const int* __restrict__ cols,
                           int* __restrict__ cnt, int nnz) {
    int i = blockIdx.x * blockDim.x + threadIdx.x;
    if (i < nnz) {
        atomicAdd(&cnt[cols[i]], 1);
        atomicAdd(&cnt[HGCN_H + rows[i]], 1);
    }
}

// ---- hierarchical exclusive scan over cnt[0..n) (in-place) ---------------
__global__ void hgcn_scan_reduce(const int* __restrict__ cnt, int* __restrict__ partial, int n) {
    __shared__ int red[SCAN_TPB];
    int base = blockIdx.x * SCAN_PER;
    int sum = 0;
    for (int k = threadIdx.x; k < SCAN_PER; k += SCAN_TPB) {
        int i = base + k;
        if (i < n) sum += cnt[i];
    }
    red[threadIdx.x] = sum; __syncthreads();
    for (int o = SCAN_TPB / 2; o > 0; o >>= 1) {
        if (threadIdx.x < o) red[threadIdx.x] += red[threadIdx.x + o];
        __syncthreads();
    }
    if (threadIdx.x == 0) partial[blockIdx.x] = red[0];
}

__global__ void hgcn_scan_partials(int* __restrict__ partial, int nb) {
    __shared__ int buf[SCAN_TPB];
    int tid = threadIdx.x;
    int x = (tid < nb) ? partial[tid] : 0;
    buf[tid] = x; __syncthreads();
    for (int o = 1; o < SCAN_TPB; o <<= 1) {
        int y = (tid >= o) ? buf[tid - o] : 0;
        __syncthreads();
        buf[tid] += y;
        __syncthreads();
    }
    if (tid < nb) partial[tid] = buf[tid] - x;   // exclusive
}

__global__ void hgcn_scan_apply(int* __restrict__ cnt, const int* __restrict__ partial, int n) {
    __shared__ int buf[SCAN_TPB];
    int base = blockIdx.x * SCAN_PER + threadIdx.x * 8;
    int v[8]; int s = 0;
    #pragma unroll
    for (int k = 0; k < 8; ++k) {
        int i = base + k;
        v[k] = (i < n) ? cnt[i] : 0;
        s += v[k];
    }
    buf[threadIdx.x] = s; __syncthreads();
    int x = s;
    for (int o = 1; o < SCAN_TPB; o <<= 1) {
        int y = (threadIdx.x >= o) ? buf[threadIdx.x - o] : 0;
        __syncthreads();
        buf[threadIdx.x] += y;
        __syncthreads();
    }
    int excl = buf[threadIdx.x] - x + partial[blockIdx.x];
    #pragma unroll
    for (int k = 0; k < 8; ++k) {
        int i = base + k;
        if (i < n) { cnt[i] = excl; excl += v[k]; }
    }
}

__device__ __forceinline__ long long hgcn_pack(float v, int other) {
    return ((long long)(unsigned)other << 32) | (unsigned)__float_as_uint(v);
}

// ---- ticketed scatter, cols only (positions [0, nnz)) --------------------
template <int PACKED>
__global__ void hgcn_scat_cols(const float* __restrict__ vals,
                               const int* __restrict__ rows, const int* __restrict__ cols,
                               int* __restrict__ cur,
                               long long* __restrict__ perm2, int* __restrict__ perm,
                               int nnz) {
    int i = blockIdx.x * blockDim.x + threadIdx.x;
    if (i < nnz) {
        int p = atomicAdd(&cur[cols[i]], 1);
        if (PACKED) perm2[p] = hgcn_pack(vals[i], rows[i]);
        else        perm[p]  = i;
    }
}

// ---- gather-reduce body: one 64-lane wave per output row -----------------
// wid uniform (readfirstlane) -> metadata loads hit the scalar pipe. PACKED:
// contiguous 8B records, s_load_dwordx16 per 8 edges. Vector pipe: one
// coalesced 512B row load + 2 FMAs per edge. Unroll x8, 8 acc chains.
template <int RELU, int PACKED>
__device__ __forceinline__ void hgcn_gather_row(
        const long long* __restrict__ perm2, const int* __restrict__ perm,
        const float* __restrict__ vals, const int* __restrict__ other,
        const int* __restrict__ cnt,
        const float* __restrict__ src, float* __restrict__ dst,
        int wid, int lane, int bucket0) {
    int bk = bucket0 + wid;
    int s_ = (bk == 0) ? 0 : cnt[bk - 1];
    int e_ = cnt[bk];

    const float2* srcv = (const float2*)src;
    float2 a[8];
    #pragma unroll
    for (int k = 0; k < 8; ++k) a[k] = make_float2(0.f, 0.f);

    int j = s_;
    for (; j + 7 < e_; j += 8) {
        float v[8]; int ix[8];
        if (PACKED) {
            #pragma unroll
            for (int k = 0; k < 8; ++k) {
                long long m = perm2[j + k];
                v[k]  = __uint_as_float((unsigned)(m & 0xffffffffLL));
                ix[k] = (int)(m >> 32);
            }
        } else {
            int e[8];
            #pragma unroll
            for (int k = 0; k < 8; ++k) e[k] = perm[j + k];
            #pragma unroll
            for (int k = 0; k < 8; ++k) { v[k] = vals[e[k]]; ix[k] = other[e[k]]; }
        }
        float2 x[8];
        #pragma unroll
        for (int k = 0; k < 8; ++k) x[k] = srcv[ix[k] * 64 + lane];
        #pragma unroll
        for (int k = 0; k < 8; ++k) { a[k].x += v[k] * x[k].x; a[k].y += v[k] * x[k].y; }
    }
    for (; j < e_; ++j) {
        float v0; int i0;
        if (PACKED) {
            long long m = perm2[j];
            v0 = __uint_as_float((unsigned)(m & 0xffffffffLL));
            i0 = (int)(m >> 32);
        } else {
            int e0 = perm[j];
            v0 = vals[e0]; i0 = other[e0];
        }
        float2 x0 = srcv[i0 * 64 + lane];
        a[0].x += v0 * x0.x; a[0].y += v0 * x0.y;
    }

    float2 r;
    r.x = ((a[0].x + a[1].x) + (a[2].x + a[3].x)) + ((a[4].x + a[5].x) + (a[6].x + a[7].x));
    r.y = ((a[0].y + a[1].y) + (a[2].y + a[3].y)) + ((a[4].y + a[5].y) + (a[6].y + a[7].y));
    if (RELU) {
        r.x = r.x >= 0.f ? r.x : 0.5f * r.x;
        r.y = r.y >= 0.f ? r.y : 0.5f * r.y;
    }
    ((float2*)dst)[wid * 64 + lane] = r;
}

// ---- fused: gather phase-1 (cols buckets -> hyper)  +  scat_rows ---------
// Independent work; interleaved block roles so the LLC-read-bound gather and
// the HBM-write-bound scatter overlap instead of serializing.
template <int PACKED>
__global__ void hgcn_g1_scatrows(long long* __restrict__ perm2, int* __restrict__ perm,
                                 int* __restrict__ cnt,
                                 const float* __restrict__ vals,
                                 const int* __restrict__ rows,
                                 const int* __restrict__ cols,
                                 const float* __restrict__ embs,
                                 float* __restrict__ hyper,
                                 int nnz, int nb_g, int nb_s) {
    int b = blockIdx.x;
    int m2 = (nb_g < nb_s ? nb_g : nb_s) * 2;
    int role, idx;
    if (b < m2) { role = b & 1; idx = b >> 1; }
    else {
        int r = b - m2;
        if (nb_g > nb_s) { role = 0; idx = (m2 >> 1) + r; }
        else             { role = 1; idx = (m2 >> 1) + r; }
    }

    if (role == 0) {
        int wid = __builtin_amdgcn_readfirstlane(idx * 4 + (int)(threadIdx.x >> 6));
        if (wid >= HGCN_H) return;
        int lane = threadIdx.x & 63;
        hgcn_gather_row<0, PACKED>(perm2, perm, vals, rows, cnt, embs, hyper, wid, lane, 0);
    } else {
        int i = idx * 256 + threadIdx.x;
        if (i < nnz) {
            int p = atomicAdd(&cnt[HGCN_H + rows[i]], 1);   // p in [nnz, 2*nnz)
            if (PACKED) perm2[p] = hgcn_pack(vals[i], cols[i]);
            else        perm[p]  = i;
        }
    }
}

// ---- gather phase-2: rows buckets -> out, with LeakyReLU -----------------
template <int PACKED>
__global__ void hgcn_gather2(const long long* __restrict__ perm2, const int* __restrict__ perm,
                             const int* __restrict__ cnt,
                             const float* __restrict__ vals, const int* __restrict__ cols,
                             const float* __restrict__ hyper, float* __restrict__ out,
                             int n_nodes) {
    int wid = __builtin_amdgcn_readfirstlane((int)(blockIdx.x * 4 + (threadIdx.x >> 6)));
    if (wid >= n_nodes) return;
    int lane = threadIdx.x & 63;
    hgcn_gather_row<1, PACKED>(perm2, perm, vals, cols, cnt, hyper, out, wid, lane, HGCN_H);
}

extern "C" void kernel_launch(void* const* d_in, const int* in_sizes, int n_in,
                              void* d_out, int out_size, void* d_ws, size_t ws_size,
                              hipStream_t stream) {
    const float* vals = (const float*)d_in[0];
    const float* embs = (const float*)d_in[1];
    const int*   rows = (const int*)d_in[2];
    const int*   cols = (const int*)d_in[3];

    const int nnz     = in_sizes[0];
    const int n_nodes = in_sizes[1] / HGCN_D;   // 100000
    const int n_all   = HGCN_H + n_nodes;       // 150000 buckets

    float* out = (float*)d_out;

    // packed layout: perm2 [2*nnz*8B] | hyper [H*D*4B] | cnt | partial  (~78 MB)
    size_t need_packed = (size_t)2 * nnz * 8 + (size_t)HGCN_H * HGCN_D * 4
                       + (size_t)n_all * 4 + 8192;
    const int packed = (ws_size >= need_packed);

    char* ws = (char*)d_ws;
    long long* perm2 = nullptr;
    int*       perm  = nullptr;
    float*     hyper;
    int*       cnt;
    int*       partial;

    if (packed) {
        perm2 = (long long*)ws;
        size_t off = (size_t)2 * nnz * 8;
        hyper = (float*)(ws + off);
        off += (size_t)HGCN_H * HGCN_D * 4;
        off = (off + 255) & ~(size_t)255;
        cnt = (int*)(ws + off);
        off += (size_t)n_all * 4;
        off = (off + 255) & ~(size_t)255;
        partial = (int*)(ws + off);
    } else {
        // fallback: hyper | perm [2*nnz*4B] | cnt | partial  (~52 MB)
        hyper = (float*)ws;
        size_t off = (size_t)HGCN_H * HGCN_D * 4;
        perm = (int*)(ws + off);
        off += (size_t)2 * nnz * 4;
        off = (off + 255) & ~(size_t)255;
        cnt = (int*)(ws + off);
        off += (size_t)n_all * 4;
        off = (off + 255) & ~(size_t)255;
        partial = (int*)(ws + off);
    }

    const int B = 256;
    int eg = (nnz + B - 1) / B;                    // 12500
    int nb = (n_all + SCAN_PER - 1) / SCAN_PER;    // 74

    hipMemsetAsync(cnt, 0, (size_t)n_all * sizeof(int), stream);
    hgcn_hist2<<<eg, B, 0, stream>>>(rows, cols, cnt, nnz);
    hgcn_scan_reduce<<<nb, SCAN_TPB, 0, stream>>>(cnt, partial, n_all);
    hgcn_scan_partials<<<1, SCAN_TPB, 0, stream>>>(partial, nb);
    hgcn_scan_apply<<<nb, SCAN_TPB, 0, stream>>>(cnt, partial, n_all);

    int nb_g = (HGCN_H + 3) / 4;                   // 12500
    int nb_s = eg;                                 // 12500

    if (packed) {
        hgcn_scat_cols<1><<<eg, B, 0, stream>>>(vals, rows, cols, cnt, perm2, perm, nnz);
        hgcn_g1_scatrows<1><<<nb_g + nb_s, B, 0, stream>>>(perm2, perm, cnt, vals, rows,
                                                           cols, embs, hyper, nnz, nb_g, nb_s);
        hgcn_gather2<1><<<(n_nodes + 3) / 4, B, 0, stream>>>(perm2, perm, cnt, vals, cols,
                                                             hyper, out, n_nodes);
    } else {
        hgcn_scat_cols<0><<<eg, B, 0, stream>>>(vals, rows, cols, cnt, perm2, perm, nnz);
        hgcn_g1_scatrows<0><<<nb_g + nb_s, B, 0, stream>>>(perm2, perm, cnt, vals, rows,
                                                           cols, embs, hyper, nnz, nb_g, nb_s);
        hgcn_gather2<0><<<(n_nodes + 3) / 4, B, 0, stream>>>(perm2, perm, cnt, vals, cols,
                                                             hyper, out, n_nodes);
    }
}

// Round 6
// 899.194 us; speedup vs baseline: 1.7132x; 1.3716x over previous
//
#include <hip/hip_runtime.h>

// HGCNConv: out = LeakyReLU_0.5( A @ (A^T @ embs) ), A sparse COO.
// N=100000, H=50000, D=128, NNZ=3200000.
//
// Counting-sort into per-bucket PACKED (val, other_idx) records, then one
// 64-lane wave per output row does a gather-reduce: contiguous scalar-pipe
// metadata loads (8B/edge), coalesced row load + FMAs per edge, unroll x8.
// Round-6 change: gather rows in BF16 (halves the dominant L2-miss traffic:
// embs converted once to bf16, hyper stored bf16; fp32 accumulation, fp32
// output). Convert fused into the histogram kernel. Fallbacks: fp32-packed,
// then edge-id, if ws_size is too small.

#define HGCN_D   128
#define HGCN_H   50000
#define SCAN_TPB 256
#define SCAN_PER 2048   // 8 elements per thread

__device__ __forceinline__ unsigned hgcn_bf16rne(float f) {
    unsigned u = __float_as_uint(f);
    return (u + 0x7fffu + ((u >> 16) & 1u)) >> 16;
}

// ---- fused histogram (+ optional embs->bf16 convert) ---------------------
// CONV: even blocks histogram, odd blocks convert (independent streams).
template <int CONV>
__global__ void hgcn_hist2(const int* __restrict__ rows, const int* __restrict__ cols,
                           int* __restrict__ cnt,
                           const float* __restrict__ embs, unsigned* __restrict__ embs16,
                           int nnz, int nelem) {
    int b = blockIdx.x;
    int role = CONV ? (b & 1) : 0;
    int idx  = CONV ? (b >> 1) : b;
    if (role == 0) {
        int i = idx * 256 + threadIdx.x;
        if (i < nnz) {
            atomicAdd(&cnt[cols[i]], 1);
            atomicAdd(&cnt[HGCN_H + rows[i]], 1);
        }
    } else {
        int t = idx * 256 + threadIdx.x;       // one float4 per thread
        int e = t * 4;
        if (e < nelem) {
            float4 x = ((const float4*)embs)[t];
            uint2 p;
            p.x = hgcn_bf16rne(x.x) | (hgcn_bf16rne(x.y) << 16);
            p.y = hgcn_bf16rne(x.z) | (hgcn_bf16rne(x.w) << 16);
            ((uint2*)embs16)[t] = p;
        }
    }
}

// ---- hierarchical exclusive scan over cnt[0..n) (in-place) ---------------
__global__ void hgcn_scan_reduce(const int* __restrict__ cnt, int* __restrict__ partial, int n) {
    __shared__ int red[SCAN_TPB];
    int base = blockIdx.x * SCAN_PER;
    int sum = 0;
    for (int k = threadIdx.x; k < SCAN_PER; k += SCAN_TPB) {
        int i = base + k;
        if (i < n) sum += cnt[i];
    }
    red[threadIdx.x] = sum; __syncthreads();
    for (int o = SCAN_TPB / 2; o > 0; o >>= 1) {
        if (threadIdx.x < o) red[threadIdx.x] += red[threadIdx.x + o];
        __syncthreads();
    }
    if (threadIdx.x == 0) partial[blockIdx.x] = red[0];
}

__global__ void hgcn_scan_partials(int* __restrict__ partial, int nb) {
    __shared__ int buf[SCAN_TPB];
    int tid = threadIdx.x;
    int x = (tid < nb) ? partial[tid] : 0;
    buf[tid] = x; __syncthreads();
    for (int o = 1; o < SCAN_TPB; o <<= 1) {
        int y = (tid >= o) ? buf[tid - o] : 0;
        __syncthreads();
        buf[tid] += y;
        __syncthreads();
    }
    if (tid < nb) partial[tid] = buf[tid] - x;   // exclusive
}

__global__ void hgcn_scan_apply(int* __restrict__ cnt, const int* __restrict__ partial, int n) {
    __shared__ int buf[SCAN_TPB];
    int base = blockIdx.x * SCAN_PER + threadIdx.x * 8;
    int v[8]; int s = 0;
    #pragma unroll
    for (int k = 0; k < 8; ++k) {
        int i = base + k;
        v[k] = (i < n) ? cnt[i] : 0;
        s += v[k];
    }
    buf[threadIdx.x] = s; __syncthreads();
    int x = s;
    for (int o = 1; o < SCAN_TPB; o <<= 1) {
        int y = (threadIdx.x >= o) ? buf[threadIdx.x - o] : 0;
        __syncthreads();
        buf[threadIdx.x] += y;
        __syncthreads();
    }
    int excl = buf[threadIdx.x] - x + partial[blockIdx.x];
    #pragma unroll
    for (int k = 0; k < 8; ++k) {
        int i = base + k;
        if (i < n) { cnt[i] = excl; excl += v[k]; }
    }
}

__device__ __forceinline__ long long hgcn_pack(float v, int other) {
    return ((long long)(unsigned)other << 32) | (unsigned)__float_as_uint(v);
}

// ---- ticketed scatter, cols only (positions [0, nnz)) --------------------
template <int PACKED>
__global__ void hgcn_scat_cols(const float* __restrict__ vals,
                               const int* __restrict__ rows, const int* __restrict__ cols,
                               int* __restrict__ cur,
                               long long* __restrict__ perm2, int* __restrict__ perm,
                               int nnz) {
    int i = blockIdx.x * blockDim.x + threadIdx.x;
    if (i < nnz) {
        int p = atomicAdd(&cur[cols[i]], 1);
        if (PACKED) perm2[p] = hgcn_pack(vals[i], rows[i]);
        else        perm[p]  = i;
    }
}

// ---- gather-reduce body: one 64-lane wave per output row -----------------
// wid uniform (readfirstlane) -> metadata loads hit the scalar pipe.
// SRC16: rows are bf16 (4B/lane), unpacked to fp32; else fp32 float2/lane.
// DST16: result stored as packed bf16 (4B/lane); else float2.
template <int RELU, int PACKED, int SRC16, int DST16>
__device__ __forceinline__ void hgcn_gather_row(
        const long long* __restrict__ perm2, const int* __restrict__ perm,
        const float* __restrict__ vals, const int* __restrict__ other,
        const int* __restrict__ cnt,
        const void* __restrict__ src, void* __restrict__ dst,
        int wid, int lane, int bucket0) {
    int bk = bucket0 + wid;
    int s_ = (bk == 0) ? 0 : cnt[bk - 1];
    int e_ = cnt[bk];

    const float2*   srcf = (const float2*)src;
    const unsigned* srcu = (const unsigned*)src;
    float2 a[8];
    #pragma unroll
    for (int k = 0; k < 8; ++k) a[k] = make_float2(0.f, 0.f);

    int j = s_;
    for (; j + 7 < e_; j += 8) {
        float v[8]; int ix[8];
        if (PACKED) {
            #pragma unroll
            for (int k = 0; k < 8; ++k) {
                long long m = perm2[j + k];
                v[k]  = __uint_as_float((unsigned)(m & 0xffffffffLL));
                ix[k] = (int)(m >> 32);
            }
        } else {
            int e[8];
            #pragma unroll
            for (int k = 0; k < 8; ++k) e[k] = perm[j + k];
            #pragma unroll
            for (int k = 0; k < 8; ++k) { v[k] = vals[e[k]]; ix[k] = other[e[k]]; }
        }
        if (SRC16) {
            unsigned u[8];
            #pragma unroll
            for (int k = 0; k < 8; ++k) u[k] = srcu[ix[k] * 64 + lane];
            #pragma unroll
            for (int k = 0; k < 8; ++k) {
                float lo = __uint_as_float(u[k] << 16);
                float hi = __uint_as_float(u[k] & 0xffff0000u);
                a[k].x += v[k] * lo; a[k].y += v[k] * hi;
            }
        } else {
            float2 x[8];
            #pragma unroll
            for (int k = 0; k < 8; ++k) x[k] = srcf[ix[k] * 64 + lane];
            #pragma unroll
            for (int k = 0; k < 8; ++k) { a[k].x += v[k] * x[k].x; a[k].y += v[k] * x[k].y; }
        }
    }
    for (; j < e_; ++j) {
        float v0; int i0;
        if (PACKED) {
            long long m = perm2[j];
            v0 = __uint_as_float((unsigned)(m & 0xffffffffLL));
            i0 = (int)(m >> 32);
        } else {
            int e0 = perm[j];
            v0 = vals[e0]; i0 = other[e0];
        }
        if (SRC16) {
            unsigned u = srcu[i0 * 64 + lane];
            a[0].x += v0 * __uint_as_float(u << 16);
            a[0].y += v0 * __uint_as_float(u & 0xffff0000u);
        } else {
            float2 x0 = srcf[i0 * 64 + lane];
            a[0].x += v0 * x0.x; a[0].y += v0 * x0.y;
        }
    }

    float2 r;
    r.x = ((a[0].x + a[1].x) + (a[2].x + a[3].x)) + ((a[4].x + a[5].x) + (a[6].x + a[7].x));
    r.y = ((a[0].y + a[1].y) + (a[2].y + a[3].y)) + ((a[4].y + a[5].y) + (a[6].y + a[7].y));
    if (RELU) {
        r.x = r.x >= 0.f ? r.x : 0.5f * r.x;
        r.y = r.y >= 0.f ? r.y : 0.5f * r.y;
    }
    if (DST16) {
        unsigned p = hgcn_bf16rne(r.x) | (hgcn_bf16rne(r.y) << 16);
        ((unsigned*)dst)[wid * 64 + lane] = p;
    } else {
        ((float2*)dst)[wid * 64 + lane] = r;
    }
}

// ---- fused: gather phase-1 (cols buckets -> hyper)  +  scat_rows ---------
template <int PACKED, int SRC16, int DST16>
__global__ void hgcn_g1_scatrows(long long* __restrict__ perm2, int* __restrict__ perm,
                                 int* __restrict__ cnt,
                                 const float* __restrict__ vals,
                                 const int* __restrict__ rows,
                                 const int* __restrict__ cols,
                                 const void* __restrict__ src,
                                 void* __restrict__ hyper,
                                 int nnz, int nb_g, int nb_s) {
    int b = blockIdx.x;
    int m2 = (nb_g < nb_s ? nb_g : nb_s) * 2;
    int role, idx;
    if (b < m2) { role = b & 1; idx = b >> 1; }
    else {
        int r = b - m2;
        if (nb_g > nb_s) { role = 0; idx = (m2 >> 1) + r; }
        else             { role = 1; idx = (m2 >> 1) + r; }
    }

    if (role == 0) {
        int wid = __builtin_amdgcn_readfirstlane(idx * 4 + (int)(threadIdx.x >> 6));
        if (wid >= HGCN_H) return;
        int lane = threadIdx.x & 63;
        hgcn_gather_row<0, PACKED, SRC16, DST16>(perm2, perm, vals, rows, cnt,
                                                 src, hyper, wid, lane, 0);
    } else {
        int i = idx * 256 + threadIdx.x;
        if (i < nnz) {
            int p = atomicAdd(&cnt[HGCN_H + rows[i]], 1);   // p in [nnz, 2*nnz)
            if (PACKED) perm2[p] = hgcn_pack(vals[i], cols[i]);
            else        perm[p]  = i;
        }
    }
}

// ---- gather phase-2: rows buckets -> out (fp32), with LeakyReLU ----------
template <int PACKED, int SRC16>
__global__ void hgcn_gather2(const long long* __restrict__ perm2, const int* __restrict__ perm,
                             const int* __restrict__ cnt,
                             const float* __restrict__ vals, const int* __restrict__ cols,
                             const void* __restrict__ hyper, float* __restrict__ out,
                             int n_nodes) {
    int wid = __builtin_amdgcn_readfirstlane((int)(blockIdx.x * 4 + (threadIdx.x >> 6)));
    if (wid >= n_nodes) return;
    int lane = threadIdx.x & 63;
    hgcn_gather_row<1, PACKED, SRC16, 0>(perm2, perm, vals, cols, cnt,
                                         hyper, out, wid, lane, HGCN_H);
}

extern "C" void kernel_launch(void* const* d_in, const int* in_sizes, int n_in,
                              void* d_out, int out_size, void* d_ws, size_t ws_size,
                              hipStream_t stream) {
    const float* vals = (const float*)d_in[0];
    const float* embs = (const float*)d_in[1];
    const int*   rows = (const int*)d_in[2];
    const int*   cols = (const int*)d_in[3];

    const int nnz     = in_sizes[0];
    const int n_nodes = in_sizes[1] / HGCN_D;   // 100000
    const int n_all   = HGCN_H + n_nodes;       // 150000 buckets
    const int nelem   = n_nodes * HGCN_D;       // 12.8M

    float* out = (float*)d_out;

    size_t sz_perm2 = (size_t)2 * nnz * 8;
    size_t sz_e16   = (size_t)nelem * 2;
    size_t sz_h16   = (size_t)HGCN_H * HGCN_D * 2;
    size_t sz_hf    = (size_t)HGCN_H * HGCN_D * 4;
    size_t sz_cnt   = (size_t)n_all * 4;

    size_t need_b16  = sz_perm2 + sz_e16 + sz_h16 + sz_cnt + 8192;   // ~90 MB
    size_t need_pk   = sz_perm2 + sz_hf + sz_cnt + 8192;             // ~78 MB
    const int mode = (ws_size >= need_b16) ? 2 : (ws_size >= need_pk ? 1 : 0);

    char* ws = (char*)d_ws;
    long long* perm2 = nullptr;
    int*       perm  = nullptr;
    unsigned*  embs16 = nullptr;
    void*      hyper;          // bf16 (mode 2) or fp32 (others)
    int*       cnt;
    int*       partial;

    if (mode == 2) {
        size_t off = 0;
        perm2 = (long long*)ws;            off += sz_perm2;
        embs16 = (unsigned*)(ws + off);    off += sz_e16;
        hyper = (void*)(ws + off);         off += sz_h16;
        off = (off + 255) & ~(size_t)255;
        cnt = (int*)(ws + off);            off += sz_cnt;
        off = (off + 255) & ~(size_t)255;
        partial = (int*)(ws + off);
    } else if (mode == 1) {
        size_t off = 0;
        perm2 = (long long*)ws;            off += sz_perm2;
        hyper = (void*)(ws + off);         off += sz_hf;
        off = (off + 255) & ~(size_t)255;
        cnt = (int*)(ws + off);            off += sz_cnt;
        off = (off + 255) & ~(size_t)255;
        partial = (int*)(ws + off);
    } else {
        size_t off = 0;
        hyper = (void*)ws;                 off += sz_hf;
        perm = (int*)(ws + off);           off += (size_t)2 * nnz * 4;
        off = (off + 255) & ~(size_t)255;
        cnt = (int*)(ws + off);            off += sz_cnt;
        off = (off + 255) & ~(size_t)255;
        partial = (int*)(ws + off);
    }

    const int B = 256;
    int eg = (nnz + B - 1) / B;                    // 12500
    int cg = (nelem / 4 + B - 1) / B;              // 12500 convert blocks
    int nb = (n_all + SCAN_PER - 1) / SCAN_PER;    // 74
    int nb_g = (HGCN_H + 3) / 4;                   // 12500
    int nb_s = eg;                                 // 12500
    int g2 = (n_nodes + 3) / 4;

    hipMemsetAsync(cnt, 0, sz_cnt, stream);

    if (mode == 2) {
        hgcn_hist2<1><<<eg + cg, B, 0, stream>>>(rows, cols, cnt, embs, embs16, nnz, nelem);
    } else {
        hgcn_hist2<0><<<eg, B, 0, stream>>>(rows, cols, cnt, embs, embs16, nnz, nelem);
    }
    hgcn_scan_reduce<<<nb, SCAN_TPB, 0, stream>>>(cnt, partial, n_all);
    hgcn_scan_partials<<<1, SCAN_TPB, 0, stream>>>(partial, nb);
    hgcn_scan_apply<<<nb, SCAN_TPB, 0, stream>>>(cnt, partial, n_all);

    if (mode == 2) {
        hgcn_scat_cols<1><<<eg, B, 0, stream>>>(vals, rows, cols, cnt, perm2, perm, nnz);
        hgcn_g1_scatrows<1, 1, 1><<<nb_g + nb_s, B, 0, stream>>>(
            perm2, perm, cnt, vals, rows, cols, (const void*)embs16, hyper, nnz, nb_g, nb_s);
        hgcn_gather2<1, 1><<<g2, B, 0, stream>>>(perm2, perm, cnt, vals, cols,
                                                 (const void*)hyper, out, n_nodes);
    } else if (mode == 1) {
        hgcn_scat_cols<1><<<eg, B, 0, stream>>>(vals, rows, cols, cnt, perm2, perm, nnz);
        hgcn_g1_scatrows<1, 0, 0><<<nb_g + nb_s, B, 0, stream>>>(
            perm2, perm, cnt, vals, rows, cols, (const void*)embs, hyper, nnz, nb_g, nb_s);
        hgcn_gather2<1, 0><<<g2, B, 0, stream>>>(perm2, perm, cnt, vals, cols,
                                                 (const void*)hyper, out, n_nodes);
    } else {
        hgcn_scat_cols<0><<<eg, B, 0, stream>>>(vals, rows, cols, cnt, perm2, perm, nnz);
        hgcn_g1_scatrows<0, 0, 0><<<nb_g + nb_s, B, 0, stream>>>(
            perm2, perm, cnt, vals, rows, cols, (const void*)embs, hyper, nnz, nb_g, nb_s);
        hgcn_gather2<0, 0><<<g2, B, 0, stream>>>(perm2, perm, cnt, vals, cols,
                                                 (const void*)hyper, out, n_nodes);
    }
}